// Round 1
// baseline (697.537 us; speedup 1.0000x reference)
//
#include <hip/hip_runtime.h>

#define B_ 4
#define C_ 128
#define H_ 256
#define W_ 256

static constexpr int    BC    = B_ * C_;                     // 512
static constexpr size_t PLANE = (size_t)H_ * W_;             // 65536
static constexpr size_t NTOT  = (size_t)B_ * C_ * H_ * W_;   // 33,554,432

// ---------------------------------------------------------------------------
// Vertical scans (up, down). Chain along H; threads map to W (contiguous) so
// every global access is a coalesced 1KiB wave transaction.
// grid = (BC, 2): y==0 -> down, y==1 -> up. block = 256 (== W).
// ---------------------------------------------------------------------------
__global__ __launch_bounds__(256) void irnn_vertical(
    const float* __restrict__ x,
    const float* __restrict__ w_up,   const float* __restrict__ b_up,
    const float* __restrict__ w_down, const float* __restrict__ b_down,
    float* __restrict__ out_up, float* __restrict__ out_down)
{
    const int w  = threadIdx.x;          // 0..255
    const int bc = blockIdx.x;           // 0..511
    const int c  = bc & (C_ - 1);
    const size_t base = (size_t)bc * PLANE + (size_t)w;

    if (blockIdx.y == 0) {
        // ---- down: out[0] = x[0]; out[h] = relu(w*out[h-1] + b + x[h])
        const float wc = w_down[c];
        const float bb = b_down[c];
        float prev = x[base];
        out_down[base] = prev;
        size_t idx = base;
        int h = 1;
        for (; h + 3 < H_; h += 4) {
            idx += W_;
            // batch the 4 independent loads ahead of the serial fma chain
            float x0 = x[idx];
            float x1 = x[idx + W_];
            float x2 = x[idx + 2 * W_];
            float x3 = x[idx + 3 * W_];
            float v0 = fmaxf(fmaf(wc, prev, bb + x0), 0.f); out_down[idx]          = v0;
            float v1 = fmaxf(fmaf(wc, v0,   bb + x1), 0.f); out_down[idx + W_]     = v1;
            float v2 = fmaxf(fmaf(wc, v1,   bb + x2), 0.f); out_down[idx + 2 * W_] = v2;
            float v3 = fmaxf(fmaf(wc, v2,   bb + x3), 0.f); out_down[idx + 3 * W_] = v3;
            prev = v3;
            idx += 3 * (size_t)W_;
        }
        for (; h < H_; ++h) {
            idx += W_;
            float v = fmaxf(fmaf(wc, prev, bb + x[idx]), 0.f);
            out_down[idx] = v;
            prev = v;
        }
    } else {
        // ---- up: out[H-1] = x[H-1]; out[h] = relu(w*out[h+1] + b + x[h])
        const float wc = w_up[c];
        const float bb = b_up[c];
        size_t idx = base + (size_t)(H_ - 1) * W_;
        float prev = x[idx];
        out_up[idx] = prev;
        int h = 1;                        // distance from top row
        for (; h + 3 < H_; h += 4) {
            idx -= W_;
            float x0 = x[idx];
            float x1 = x[idx - W_];
            float x2 = x[idx - 2 * W_];
            float x3 = x[idx - 3 * W_];
            float v0 = fmaxf(fmaf(wc, prev, bb + x0), 0.f); out_up[idx]          = v0;
            float v1 = fmaxf(fmaf(wc, v0,   bb + x1), 0.f); out_up[idx - W_]     = v1;
            float v2 = fmaxf(fmaf(wc, v1,   bb + x2), 0.f); out_up[idx - 2 * W_] = v2;
            float v3 = fmaxf(fmaf(wc, v2,   bb + x3), 0.f); out_up[idx - 3 * W_] = v3;
            prev = v3;
            idx -= 3 * (size_t)W_;
        }
        for (; h < H_; ++h) {
            idx -= W_;
            float v = fmaxf(fmaf(wc, prev, bb + x[idx]), 0.f);
            out_up[idx] = v;
            prev = v;
        }
    }
}

// ---------------------------------------------------------------------------
// Horizontal scans (right, left), fused: input read ONCE for both directions.
// Block = 256 threads handles 32 rows x full W for one (b,c) plane tile.
//   phase 0: coalesced float4 load of 32x256 into LDS (stride 257 ->
//            bank = (r + w) % 32, conflict-free for the scan phase)
//   per 64-col chunk: wave0 scans (lanes 0-31 right, 32-63 left, branch-free),
//            stages results in LDS (stride 65), then all 256 threads flush
//            both directions' chunks with coalesced float4 stores.
// grid = BC * (H/32) = 4096 blocks.
// ---------------------------------------------------------------------------
__global__ __launch_bounds__(256) void irnn_horizontal(
    const float* __restrict__ x,
    const float* __restrict__ w_right, const float* __restrict__ b_right,
    const float* __restrict__ w_left,  const float* __restrict__ b_left,
    float* __restrict__ out_right, float* __restrict__ out_left)
{
    __shared__ float xs[32 * 257];     // 32,896 B
    __shared__ float os[2][32 * 65];   // 2 x 8,320 B  (0 = right, 1 = left)

    const int tid = threadIdx.x;
    const int blk = blockIdx.x;
    const int bc  = blk >> 3;               // 0..511
    const int h0  = (blk & 7) * 32;         // row tile base
    const int c   = bc & (C_ - 1);
    const float* xplane = x + (size_t)bc * PLANE;

    // ---- load 32 rows x 256 cols (2048 float4s, 8 per thread), coalesced
    #pragma unroll
    for (int k = 0; k < 8; ++k) {
        int i  = tid + k * 256;             // float4 index 0..2047
        int r  = i >> 6;                    // 64 float4 per row
        int wq = i & 63;
        float4 v = *(const float4*)(xplane + (size_t)(h0 + r) * W_ + wq * 4);
        float* dp = &xs[r * 257 + wq * 4];
        dp[0] = v.x; dp[1] = v.y; dp[2] = v.z; dp[3] = v.w;
    }
    __syncthreads();

    const bool is_scan = (tid < 64);
    const int  r       = tid & 31;
    const bool is_left = (tid & 32) != 0;   // meaningful only for tid<64
    float wc = 0.f, bcf = 0.f;
    if (is_scan) {
        wc  = is_left ? w_left[c] : w_right[c];
        bcf = is_left ? b_left[c] : b_right[c];
    }
    const int    wstart = is_left ? (W_ - 1) : 0;
    const int    sgn    = is_left ? -1 : 1;
    const float* xrow   = &xs[r * 257];
    float*       orow   = &os[is_left ? 1 : 0][r * 65];
    float prev = 0.f;

    for (int ch = 0; ch < 4; ++ch) {
        if (is_scan) {
            #pragma unroll 8
            for (int j = 0; j < 64; ++j) {
                int t = ch * 64 + j;        // scan time 0..255
                int w = wstart + sgn * t;   // right: t ; left: 255-t
                float xv = xrow[w];
                float v  = fmaxf(fmaf(wc, prev, bcf + xv), 0.f);
                if (t == 0) v = xv;         // boundary slice = input (no relu)
                orow[w & 63] = v;           // chunk-local position
                prev = v;
            }
        }
        __syncthreads();
        // ---- flush both directions' chunks: 1024 float4s, 4 per thread
        #pragma unroll
        for (int k = 0; k < 4; ++k) {
            int i  = tid + k * 256;         // 0..1023
            int d  = i >> 9;                // 0 = right, 1 = left
            int ii = i & 511;
            int rr = ii >> 4;               // 0..31
            int wq = ii & 15;               // 16 float4 per 64-col chunk
            const float* op = &os[d][rr * 65 + wq * 4];
            float4 v4 = make_float4(op[0], op[1], op[2], op[3]);
            int    wb  = d ? (3 - ch) * 64 : ch * 64;   // global col base
            float* dst = d ? out_left : out_right;
            *(float4*)(dst + (size_t)bc * PLANE + (size_t)(h0 + rr) * W_ + wb + wq * 4) = v4;
        }
        __syncthreads();
    }
}

// ---------------------------------------------------------------------------
extern "C" void kernel_launch(void* const* d_in, const int* in_sizes, int n_in,
                              void* d_out, int out_size, void* d_ws, size_t ws_size,
                              hipStream_t stream) {
    // setup_inputs() dict order: input, w_up, b_up, w_right, b_right,
    //                            w_down, b_down, w_left, b_left
    const float* x       = (const float*)d_in[0];
    const float* w_up    = (const float*)d_in[1];
    const float* b_up    = (const float*)d_in[2];
    const float* w_right = (const float*)d_in[3];
    const float* b_right = (const float*)d_in[4];
    const float* w_down  = (const float*)d_in[5];
    const float* b_down  = (const float*)d_in[6];
    const float* w_left  = (const float*)d_in[7];
    const float* b_left  = (const float*)d_in[8];

    float* out       = (float*)d_out;       // [up | right | down | left]
    float* out_up    = out;
    float* out_right = out + NTOT;
    float* out_down  = out + 2 * NTOT;
    float* out_left  = out + 3 * NTOT;

    irnn_vertical<<<dim3(BC, 2), dim3(256), 0, stream>>>(
        x, w_up, b_up, w_down, b_down, out_up, out_down);

    irnn_horizontal<<<dim3(BC * (H_ / 32)), dim3(256), 0, stream>>>(
        x, w_right, b_right, w_left, b_left, out_right, out_left);
}